// Round 15
// baseline (1247.528 us; speedup 1.0000x reference)
//
#include <hip/hip_runtime.h>
#include <cstdint>

#define BB 256
#define TT 1000
#define DD 256
#define SS 10
#define HH 64
#define CC 100
// 2*log2(e): accumulate z2' = PRE*z so tanh(z) = 1 - 2/(exp2(z2')+1)
#define PRE 2.885390081777927f
#define PBS 400  // proj blocks per segment

typedef float f32x2 __attribute__((ext_vector_type(2)));
typedef float f32x4 __attribute__((ext_vector_type(4)));

__device__ __forceinline__ f32x2 lo2(f32x4 v) {
  return __builtin_shufflevector(v, v, 0, 1);
}
__device__ __forceinline__ f32x2 hi2(f32x4 v) {
  return __builtin_shufflevector(v, v, 2, 3);
}

// ---------------------------------------------------------------------------
// proj body (R13-proven, 128us as a standalone kernel):
// xp[b,t,h] = PRE*(x . W_ih + b_ih + b_hh) for one (segment s, 64-row tile r0)
// ---------------------------------------------------------------------------
__device__ __forceinline__ void proj_body(
    const float* __restrict__ x, const float* __restrict__ W_ih,
    const float* __restrict__ b_ih, const float* __restrict__ b_hh,
    float* __restrict__ xp, int s, int r0, int tid,
    float (*As)[68], float (*Bs)[68]) {
  const int ty = tid >> 4, tx = tid & 15;
  const int ty4 = ty * 4, tx4 = tx * 4;
  float acc[4][4] = {{0.f, 0.f, 0.f, 0.f}};

  for (int kc = 0; kc < 4; ++kc) {
#pragma unroll
    for (int m = 0; m < 4; ++m) {
      int f = m * 256 + tid;
      int row = f >> 4, kq = f & 15;
      int r = r0 + row;
      int b = r / CC, c = r - b * CC;
      const float4 av = *(const float4*)(
          x + ((size_t)b * TT + s * CC + c) * DD + kc * 64 + kq * 4);
      *(float4*)&As[row][kq * 4] = av;
      const float4 wv = *(const float4*)(
          W_ih + ((size_t)s * HH + row) * DD + kc * 64 + kq * 4);
      *(float4*)&Bs[row][kq * 4] = wv;
    }
    __syncthreads();
#pragma unroll 4
    for (int k = 0; k < 64; k += 4) {
      float4 a[4], w[4];
#pragma unroll
      for (int i = 0; i < 4; ++i) a[i] = *(const float4*)&As[ty4 + i][k];
#pragma unroll
      for (int j = 0; j < 4; ++j) w[j] = *(const float4*)&Bs[tx4 + j][k];
#pragma unroll
      for (int i = 0; i < 4; ++i)
#pragma unroll
        for (int j = 0; j < 4; ++j)
          acc[i][j] += a[i].x * w[j].x + a[i].y * w[j].y +
                       a[i].z * w[j].z + a[i].w * w[j].w;
    }
    __syncthreads();
  }

  const float4 b1 = *(const float4*)(b_ih + s * HH + tx4);
  const float4 b2 = *(const float4*)(b_hh + s * HH + tx4);
#pragma unroll
  for (int i = 0; i < 4; ++i) {
    int r = r0 + ty4 + i;
    int b = r / CC, c = r - b * CC;
    float4 o;
    o.x = PRE * (acc[i][0] + b1.x + b2.x);
    o.y = PRE * (acc[i][1] + b1.y + b2.y);
    o.z = PRE * (acc[i][2] + b1.z + b2.z);
    o.w = PRE * (acc[i][3] + b1.w + b2.w);
    *(float4*)(xp + ((size_t)b * TT + s * CC + c) * HH + tx4) = o;
  }
}

// ---------------------------------------------------------------------------
// rnn body (R13-proven, 205us): single wave per b, pk_fma step, fused head.
// Optional flags: acquire-spin until segment s's 400 proj blocks published.
// ---------------------------------------------------------------------------
__device__ __forceinline__ void rnn_body(
    const float* __restrict__ xp, const float* __restrict__ W_hh,
    const float* __restrict__ fc_w, const float* __restrict__ fc_b,
    float* __restrict__ y, int* flags, int b, int lane,
    float (*hist)[68]) {
  hist[CC - 1][lane] = 0.f;  // h0 = 0, read via cp at s=0,c=0

  f32x2 Wp[32];
  for (int s = 0; s < SS; ++s) {
    const float* wr = W_hh + ((size_t)s * HH + lane) * HH;
#pragma unroll
    for (int j = 0; j < 16; ++j) {
      float4 v = *(const float4*)(wr + 4 * j);
      Wp[2 * j]     = (f32x2){PRE * v.x, PRE * v.y};
      Wp[2 * j + 1] = (f32x2){PRE * v.z, PRE * v.w};
    }
    // wait for segment s's xp to be published (acquire pairs with the
    // release fetch_adds of all 400 producer blocks -> release sequence)
    if (flags) {
      while (__hip_atomic_load(&flags[s], __ATOMIC_ACQUIRE,
                               __HIP_MEMORY_SCOPE_AGENT) < PBS)
        __builtin_amdgcn_s_sleep(2);
    }
    const float* xps = xp + ((size_t)b * TT + s * CC) * HH + lane;

    float xq0 = xps[0 * HH];
    float xq1 = xps[1 * HH];
    float xq2 = xps[2 * HH];
    float xq3 = xps[3 * HH];

    float h = 0.f;
    for (int c4 = 0; c4 < 25; ++c4) {
#pragma unroll
      for (int u = 0; u < 4; ++u) {
        const int c = c4 * 4 + u;
        const int cp = (c == 0) ? CC - 1 : c - 1;
        const float xv = (u == 0) ? xq0 : (u == 1) ? xq1 : (u == 2) ? xq2 : xq3;
        f32x2 acc0 = {xv, 0.f};
        f32x2 acc1 = {0.f, 0.f};
#pragma unroll
        for (int j4 = 0; j4 < 16; ++j4) {
          const f32x4 hv = *(const f32x4*)&hist[cp][j4 * 4];
          acc0 = __builtin_elementwise_fma(Wp[2 * j4], lo2(hv), acc0);
          acc1 = __builtin_elementwise_fma(Wp[2 * j4 + 1], hi2(hv), acc1);
        }
        const f32x2 t = acc0 + acc1;
        const float z2 = t.x + t.y;          // = PRE * z
        const float e = __builtin_amdgcn_exp2f(z2);
        h = 1.f - 2.f * __builtin_amdgcn_rcpf(e + 1.f);
        hist[c][lane] = h;
        if (c4 < 24) {
          const float xn = xps[(c + 4) * HH];
          if (u == 0) xq0 = xn;
          else if (u == 1) xq1 = xn;
          else if (u == 2) xq2 = xn;
          else xq3 = xn;
        }
      }
    }

    // fused head: lane l -> y[b, s*CC + l]
    const float fb = fc_b[s];
    const float* fw = fc_w + s * HH;  // wave-uniform
#pragma unroll
    for (int base = 0; base < CC; base += 64) {
      int l = base + lane;
      if (l < CC) {
        float z = fb;
#pragma unroll
        for (int i = 0; i < 64; i += 4) {
          const float4 hv = *(const float4*)&hist[l][i];
          z += hv.x * fw[i] + hv.y * fw[i + 1] + hv.z * fw[i + 2] +
               hv.w * fw[i + 3];
        }
        y[(size_t)b * TT + s * CC + l] =
            __builtin_amdgcn_rcpf(1.f + __expf(-z));
      }
    }
  }
}

// ---------------------------------------------------------------------------
// MEGA kernel: grid = [0,256) rnn-role blocks (dispatched FIRST, so they are
// resident and waiting) + [256, 256+4000) proj-role blocks in segment-major
// order. Producer blocks publish via block-release (threadfence + barrier +
// one agent-scope RELEASE fetch_add); consumers acquire-spin per segment.
// Deadlock-free: rnn blocks hold 1 wave + 35KB LDS each, leaving room for
// >=3 proj blocks per CU -> producers always schedulable and progress.
// ---------------------------------------------------------------------------
__global__ __launch_bounds__(256, 1) void mega_kernel(
    const float* __restrict__ x, const float* __restrict__ W_ih,
    const float* __restrict__ W_hh, const float* __restrict__ b_ih,
    const float* __restrict__ b_hh, const float* __restrict__ fc_w,
    const float* __restrict__ fc_b, float* __restrict__ xp,
    int* __restrict__ flags, float* __restrict__ y) {
  __shared__ union {
    struct { float As[64][68]; float Bs[64][68]; } p;
    float hist[CC][68];
  } sm;
  const int bid = blockIdx.x;
  const int tid = threadIdx.x;

  if (bid >= BB) {
    // ---- proj role
    const int pb = bid - BB;
    const int s = pb / PBS;          // segment-major: seg 0 blocks first
    const int r0 = (pb % PBS) * 64;
    proj_body(x, W_ih, b_ih, b_hh, xp, s, r0, tid, sm.p.As, sm.p.Bs);
    __threadfence();                 // each thread: make my stores visible
    __syncthreads();                 // block-wide: all stores fenced
    if (tid == 0)
      __hip_atomic_fetch_add(&flags[s], 1, __ATOMIC_RELEASE,
                             __HIP_MEMORY_SCOPE_AGENT);
  } else {
    // ---- rnn role (single wave; extra waves exit, no barriers here)
    if (tid >= 64) return;
    rnn_body(xp, W_hh, fc_w, fc_b, y, flags, bid, tid, sm.hist);
  }
}

__global__ void zero_flags(int* f) {
  if (threadIdx.x < 16) f[threadIdx.x] = 0;
}

// Fallback wrappers (sequential R13 path if workspace lacks flag space)
__global__ __launch_bounds__(256) void proj_kernel(
    const float* __restrict__ x, const float* __restrict__ W_ih,
    const float* __restrict__ b_ih, const float* __restrict__ b_hh,
    float* __restrict__ xp) {
  __shared__ float As[64][68];
  __shared__ float Bs[64][68];
  proj_body(x, W_ih, b_ih, b_hh, xp, blockIdx.y, blockIdx.x * 64,
            threadIdx.x, As, Bs);
}
__global__ __launch_bounds__(64, 1) void rnn_kernel(
    const float* __restrict__ xp, const float* __restrict__ W_hh,
    const float* __restrict__ fc_w, const float* __restrict__ fc_b,
    float* __restrict__ y) {
  __shared__ float hist[CC][68];
  rnn_body(xp, W_hh, fc_w, fc_b, y, nullptr, blockIdx.x, threadIdx.x, hist);
}

extern "C" void kernel_launch(void* const* d_in, const int* in_sizes, int n_in,
                              void* d_out, int out_size, void* d_ws,
                              size_t ws_size, hipStream_t stream) {
  const float* x    = (const float*)d_in[0];
  const float* W_ih = (const float*)d_in[1];
  const float* W_hh = (const float*)d_in[2];
  const float* b_ih = (const float*)d_in[3];
  const float* b_hh = (const float*)d_in[4];
  const float* fc_w = (const float*)d_in[5];
  const float* fc_b = (const float*)d_in[6];
  float* y  = (float*)d_out;
  float* xp = (float*)d_ws;  // [B][T][H] fp32 = 65,536,000 B
  const size_t XPB = (size_t)BB * TT * HH * sizeof(float);

  if (ws_size >= XPB + 64) {
    int* flags = (int*)((char*)d_ws + XPB);
    zero_flags<<<1, 64, 0, stream>>>(flags);
    mega_kernel<<<BB + SS * PBS, 256, 0, stream>>>(
        x, W_ih, W_hh, b_ih, b_hh, fc_w, fc_b, xp, flags, y);
  } else {
    proj_kernel<<<dim3(PBS, SS), 256, 0, stream>>>(x, W_ih, b_ih, b_hh, xp);
    rnn_kernel<<<BB, 64, 0, stream>>>(xp, W_hh, fc_w, fc_b, y);
  }
}

// Round 16
// 314.601 us; speedup vs baseline: 3.9654x; 3.9654x over previous
//
#include <hip/hip_runtime.h>
#include <cstdint>

#define BB 256
#define TT 1000
#define DD 256
#define SS 10
#define HH 64
#define CC 100
// 2*log2(e): accumulate z2' = PRE*z so tanh(z) = 1 - 2/(exp2(z2')+1)
#define PRE 2.885390081777927f

typedef float f32x2 __attribute__((ext_vector_type(2)));
typedef float f32x4 __attribute__((ext_vector_type(4)));

__device__ __forceinline__ f32x2 lo2(f32x4 v) {
  return __builtin_shufflevector(v, v, 0, 1);
}
__device__ __forceinline__ f32x2 hi2(f32x4 v) {
  return __builtin_shufflevector(v, v, 2, 3);
}

// ---------------------------------------------------------------------------
// Kernel 1: input projection  xp[b,t,h] = PRE*(x . W_ih + b_ih + b_hh)
// R15 discovery: Bs reads were 8-way bank-conflicted since R0 (rows 4tx+j at
// fixed col k -> banks (16tx+68j+k)%32 hit only 2 bank-quads). Fixes:
//  (a) XOR swizzle Bs cols by ((row>>2)&7)<<2: read banks for tx=0..7 =
//      {0,20,8,28,16,4,24,12} = all 32 banks once; tx=8..15 alias 2-way(free).
//  (b) pk_fma inner loop: acc2[i][j] f32x2 accumulates k-pairs via lo2/hi2 of
//      the same b128 reads (no repack); 64 v_fmac -> 32 v_pk_fma per k-iter.
// As untouched (per-wave rows span 2 bank-quads -> 2-way = free).
// ---------------------------------------------------------------------------
__global__ __launch_bounds__(256) void proj_kernel(
    const float* __restrict__ x, const float* __restrict__ W_ih,
    const float* __restrict__ b_ih, const float* __restrict__ b_hh,
    float* __restrict__ xp) {
  __shared__ float As[64][68];
  __shared__ float Bs[64][68];
  const int s = blockIdx.y;
  const int r0 = blockIdx.x * 64;
  const int tid = threadIdx.x;
  const int ty = tid >> 4, tx = tid & 15;
  const int ty4 = ty * 4, tx4 = tx * 4;
  const int bswz = (tx & 7) << 2;  // read-side col XOR (== ((row>>2)&7)<<2)
  f32x2 acc2[4][4];
#pragma unroll
  for (int i = 0; i < 4; ++i)
#pragma unroll
    for (int j = 0; j < 4; ++j) acc2[i][j] = (f32x2){0.f, 0.f};

  for (int kc = 0; kc < 4; ++kc) {
#pragma unroll
    for (int m = 0; m < 4; ++m) {
      int f = m * 256 + tid;
      int row = f >> 4, kq = f & 15;
      int r = r0 + row;
      int b = r / CC, c = r - b * CC;
      const float4 av = *(const float4*)(
          x + ((size_t)b * TT + s * CC + c) * DD + kc * 64 + kq * 4);
      *(float4*)&As[row][kq * 4] = av;
      const float4 wv = *(const float4*)(
          W_ih + ((size_t)s * HH + row) * DD + kc * 64 + kq * 4);
      *(float4*)&Bs[row][(kq * 4) ^ (((row >> 2) & 7) << 2)] = wv;
    }
    __syncthreads();
#pragma unroll 4
    for (int k = 0; k < 64; k += 4) {
      const int kx = k ^ bswz;
      f32x4 a[4], w[4];
#pragma unroll
      for (int i = 0; i < 4; ++i) a[i] = *(const f32x4*)&As[ty4 + i][k];
#pragma unroll
      for (int j = 0; j < 4; ++j) w[j] = *(const f32x4*)&Bs[tx4 + j][kx];
#pragma unroll
      for (int i = 0; i < 4; ++i)
#pragma unroll
        for (int j = 0; j < 4; ++j) {
          acc2[i][j] = __builtin_elementwise_fma(lo2(a[i]), lo2(w[j]), acc2[i][j]);
          acc2[i][j] = __builtin_elementwise_fma(hi2(a[i]), hi2(w[j]), acc2[i][j]);
        }
    }
    __syncthreads();
  }

  const float4 b1 = *(const float4*)(b_ih + s * HH + tx4);
  const float4 b2 = *(const float4*)(b_hh + s * HH + tx4);
#pragma unroll
  for (int i = 0; i < 4; ++i) {
    int r = r0 + ty4 + i;
    int b = r / CC, c = r - b * CC;
    float4 o;
    o.x = PRE * ((acc2[i][0].x + acc2[i][0].y) + b1.x + b2.x);
    o.y = PRE * ((acc2[i][1].x + acc2[i][1].y) + b1.y + b2.y);
    o.z = PRE * ((acc2[i][2].x + acc2[i][2].y) + b1.z + b2.z);
    o.w = PRE * ((acc2[i][3].x + acc2[i][3].y) + b1.w + b2.w);
    *(float4*)(xp + ((size_t)b * TT + s * CC + c) * HH + tx4) = o;
  }
}

// ---------------------------------------------------------------------------
// Kernel 2: recurrence + fused head (R13-proven, 205us). UNTOUCHED.
// Single wave per b; 16 ds_read_b128 broadcast + 32 v_pk_fma_f32 per step;
// exp2-prescaled tanh; 4-deep xp ring; per-segment fused head.
// ---------------------------------------------------------------------------
__global__ __launch_bounds__(64, 1) void rnn_kernel(
    const float* __restrict__ xp, const float* __restrict__ W_hh,
    const float* __restrict__ fc_w, const float* __restrict__ fc_b,
    float* __restrict__ y) {
  __shared__ float hist[CC][68];
  const int b = blockIdx.x;
  const int lane = threadIdx.x;
  hist[CC - 1][lane] = 0.f;  // h0 = 0, read via cp at s=0,c=0

  f32x2 Wp[32];
  float h = 0.f;
  for (int s = 0; s < SS; ++s) {
    const float* wr = W_hh + ((size_t)s * HH + lane) * HH;
#pragma unroll
    for (int j = 0; j < 16; ++j) {
      float4 v = *(const float4*)(wr + 4 * j);
      Wp[2 * j]     = (f32x2){PRE * v.x, PRE * v.y};
      Wp[2 * j + 1] = (f32x2){PRE * v.z, PRE * v.w};
    }
    const float* xps = xp + ((size_t)b * TT + s * CC) * HH + lane;

    float xq0 = xps[0 * HH];
    float xq1 = xps[1 * HH];
    float xq2 = xps[2 * HH];
    float xq3 = xps[3 * HH];

    for (int c4 = 0; c4 < 25; ++c4) {
#pragma unroll
      for (int u = 0; u < 4; ++u) {
        const int c = c4 * 4 + u;
        const int cp = (c == 0) ? CC - 1 : c - 1;
        const float xv = (u == 0) ? xq0 : (u == 1) ? xq1 : (u == 2) ? xq2 : xq3;
        f32x2 acc0 = {xv, 0.f};
        f32x2 acc1 = {0.f, 0.f};
#pragma unroll
        for (int j4 = 0; j4 < 16; ++j4) {
          const f32x4 hv = *(const f32x4*)&hist[cp][j4 * 4];
          acc0 = __builtin_elementwise_fma(Wp[2 * j4], lo2(hv), acc0);
          acc1 = __builtin_elementwise_fma(Wp[2 * j4 + 1], hi2(hv), acc1);
        }
        const f32x2 t = acc0 + acc1;
        const float z2 = t.x + t.y;          // = PRE * z
        const float e = __builtin_amdgcn_exp2f(z2);
        h = 1.f - 2.f * __builtin_amdgcn_rcpf(e + 1.f);
        hist[c][lane] = h;
        if (c4 < 24) {
          const float xn = xps[(c + 4) * HH];
          if (u == 0) xq0 = xn;
          else if (u == 1) xq1 = xn;
          else if (u == 2) xq2 = xn;
          else xq3 = xn;
        }
      }
    }

    // fused head for this segment: lane l -> y[b, s*CC + l]
    const float fb = fc_b[s];
    const float* fw = fc_w + s * HH;  // wave-uniform
#pragma unroll
    for (int base = 0; base < CC; base += 64) {
      int l = base + lane;
      if (l < CC) {
        float z = fb;
#pragma unroll
        for (int i = 0; i < 64; i += 4) {
          const float4 hv = *(const float4*)&hist[l][i];
          z += hv.x * fw[i] + hv.y * fw[i + 1] + hv.z * fw[i + 2] +
               hv.w * fw[i + 3];
        }
        y[(size_t)b * TT + s * CC + l] =
            __builtin_amdgcn_rcpf(1.f + __expf(-z));
      }
    }
  }
}

extern "C" void kernel_launch(void* const* d_in, const int* in_sizes, int n_in,
                              void* d_out, int out_size, void* d_ws,
                              size_t ws_size, hipStream_t stream) {
  const float* x    = (const float*)d_in[0];
  const float* W_ih = (const float*)d_in[1];
  const float* W_hh = (const float*)d_in[2];
  const float* b_ih = (const float*)d_in[3];
  const float* b_hh = (const float*)d_in[4];
  const float* fc_w = (const float*)d_in[5];
  const float* fc_b = (const float*)d_in[6];
  float* y  = (float*)d_out;
  float* xp = (float*)d_ws;  // [B][T][H] fp32 = 65.5 MB

  proj_kernel<<<dim3(400, 10), 256, 0, stream>>>(x, W_ih, b_ih, b_hh, xp);
  rnn_kernel<<<256, 64, 0, stream>>>(xp, W_hh, fc_w, fc_b, y);
}